// Round 1
// baseline (437.872 us; speedup 1.0000x reference)
//
#include <hip/hip_runtime.h>

// CausalSelfAttention on MI355X: bf16 MFMA pipeline.
// B=4, S=2048, D=1024, H=16, hd=64. fp32 in/out, bf16 internal compute.

#define DEV __device__ __forceinline__

typedef unsigned short u16;
typedef u16   u16x8 __attribute__((ext_vector_type(8)));
typedef u16   u16x4 __attribute__((ext_vector_type(4)));
typedef float f32x4v __attribute__((ext_vector_type(4)));
typedef __bf16 bf16x8 __attribute__((ext_vector_type(8)));

#define BB 4
#define SS 2048
#define DD 1024
#define HH 16
#define HD 64
#define MM (BB*SS)          // 8192
#define N3D (3*DD)          // 3072
#define L2E 1.44269504088896340736f

DEV u16 f2bf(float f) {
  unsigned u = __builtin_bit_cast(unsigned, f);
  return (u16)((u + 0x7FFFu + ((u >> 16) & 1u)) >> 16);
}
DEV float bf2f(u16 h) { return __builtin_bit_cast(float, (unsigned)h << 16); }

DEV f32x4v mfma16(u16x8 a, u16x8 b, f32x4v c) {
  return __builtin_amdgcn_mfma_f32_16x16x32_bf16(
      __builtin_bit_cast(bf16x8, a), __builtin_bit_cast(bf16x8, b), c, 0, 0, 0);
}

// async global->LDS, 16B per lane. LDS dest must be linear in lane order.
DEV void async16(const void* g, void* l) {
  __builtin_amdgcn_global_load_lds(
      (const __attribute__((address_space(1))) void*)g,
      (__attribute__((address_space(3))) void*)l, 16, 0, 0);
}

// ---------------- 1. fp32 -> bf16 convert (vectorized, grid-stride) ----------
__global__ void convert_f32_bf16(const float* __restrict__ in, u16* __restrict__ out,
                                 long long n) {
  long long i = (long long)blockIdx.x * blockDim.x + threadIdx.x;
  long long stride = (long long)gridDim.x * blockDim.x;
  for (long long j = i * 4; j < n; j += stride * 4) {
    f32x4v v = *(const f32x4v*)(in + j);
    u16x4 o;
    o.x = f2bf(v.x); o.y = f2bf(v.y); o.z = f2bf(v.z); o.w = f2bf(v.w);
    *(u16x4*)(out + j) = o;
  }
}

// ---------------- 2. weight transpose: W[K][N] f32 -> Wt[N][K] bf16 ----------
__global__ void transpose_w(const float* __restrict__ W, u16* __restrict__ Wt,
                            int K, int N) {
  __shared__ float t[32][33];
  int n0 = blockIdx.x * 32, k0 = blockIdx.y * 32;
  for (int i = threadIdx.y; i < 32; i += 8)
    t[i][threadIdx.x] = W[(long long)(k0 + i) * N + n0 + threadIdx.x];
  __syncthreads();
  for (int i = threadIdx.y; i < 32; i += 8)
    Wt[(long long)(n0 + i) * K + k0 + threadIdx.x] = f2bf(t[threadIdx.x][i]);
}

// ---------------- 3. GEMM: C[M][N] = A[M][K] * Bt[N][K]^T + bias -------------
// 128x128 tile, BK=64, 4 waves (each 64x64), 16x16x32 bf16 MFMA (m97 structure).
__global__ __launch_bounds__(256) void gemm_kernel(
    const u16* __restrict__ A, const u16* __restrict__ Bt,
    const float* __restrict__ bias, void* __restrict__ Cout,
    int Ndim, int Kdim, int bf16out) {
  __shared__ __align__(16) u16 As[128 * 64];
  __shared__ __align__(16) u16 Bs[128 * 64];

  const int tid = threadIdx.x;
  const int lane = tid & 63, wid = tid >> 6;
  const int l15 = lane & 15, lg = lane >> 4;
  const int rb = blockIdx.y * 128, cb = blockIdx.x * 128;
  const int wr = (wid >> 1) * 64, wc = (wid & 1) * 64;

  f32x4v acc[4][4] = {};

  const int scol = (tid & 7) * 8;     // k-offset within tile this thread fetches
  const int srow = tid >> 3;          // base row (0..31), +32 per issue

  for (int kt = 0; kt < Kdim; kt += 64) {
#pragma unroll
    for (int i = 0; i < 4; ++i) {
      int row = i * 32 + srow;
      async16(A + (long long)(rb + row) * Kdim + kt + scol, (char*)As + i * 4096 + tid * 16);
      async16(Bt + (long long)(cb + row) * Kdim + kt + scol, (char*)Bs + i * 4096 + tid * 16);
    }
    __syncthreads();
#pragma unroll
    for (int kk = 0; kk < 2; ++kk) {
      u16x8 a[4], b[4];
#pragma unroll
      for (int mi = 0; mi < 4; ++mi)
        a[mi] = *(const u16x8*)&As[(wr + mi * 16 + l15) * 64 + kk * 32 + lg * 8];
#pragma unroll
      for (int ni = 0; ni < 4; ++ni)
        b[ni] = *(const u16x8*)&Bs[(wc + ni * 16 + l15) * 64 + kk * 32 + lg * 8];
#pragma unroll
      for (int mi = 0; mi < 4; ++mi)
#pragma unroll
        for (int ni = 0; ni < 4; ++ni)
          acc[mi][ni] = mfma16(a[mi], b[ni], acc[mi][ni]);
    }
    __syncthreads();
  }

#pragma unroll
  for (int mi = 0; mi < 4; ++mi)
#pragma unroll
    for (int ni = 0; ni < 4; ++ni) {
      int col = cb + wc + ni * 16 + l15;
      float bv = bias[col];
#pragma unroll
      for (int r = 0; r < 4; ++r) {
        int row = rb + wr + mi * 16 + lg * 4 + r;
        float v = acc[mi][ni][r] + bv;
        if (bf16out) ((u16*)Cout)[(long long)row * Ndim + col] = f2bf(v);
        else         ((float*)Cout)[(long long)row * Ndim + col] = v;
      }
    }
}

// ---------------- 4. pack Q,K: qkv[8192][3072] -> per-head [BH][S][64] -------
// Q scaled by 1/8 (exact in bf16).
__global__ void pack_qk(const u16* __restrict__ qkv, u16* __restrict__ Qw,
                        u16* __restrict__ Kw) {
  int sglob = blockIdx.x;
  int c = threadIdx.x * 8;  // 0..2047 (Q and K halves)
  u16x8 v = *(const u16x8*)(qkv + (long long)sglob * N3D + c);
  int part = c >> 10;
  int h = (c & 1023) >> 6;
  int d = c & 63;
  int b = sglob >> 11;
  int s = sglob & 2047;
  long long dst = ((long long)(b * HH + h) * SS + s) * HD + d;
  if (part == 0) {
#pragma unroll
    for (int j = 0; j < 8; ++j) v[j] = f2bf(bf2f(v[j]) * 0.125f);
    *(u16x8*)(Qw + dst) = v;
  } else {
    *(u16x8*)(Kw + dst) = v;
  }
}

// ---------------- 5. V transpose: qkv V part -> Vt[BH][64][S] ----------------
__global__ void transpose_v(const u16* __restrict__ qkv, u16* __restrict__ Vt) {
  __shared__ u16 t[32][33];
  int s0 = blockIdx.x * 32, d0 = blockIdx.y * 32, bh = blockIdx.z;
  int b = bh >> 4, h = bh & 15;
  for (int i = threadIdx.y; i < 32; i += 8)
    t[i][threadIdx.x] =
        qkv[(long long)(b * SS + s0 + i) * N3D + 2 * DD + h * HD + d0 + threadIdx.x];
  __syncthreads();
  for (int i = threadIdx.y; i < 32; i += 8)
    Vt[((long long)bh * HD + d0 + i) * SS + s0 + threadIdx.x] = t[threadIdx.x][i];
}

// ---------------- 6. flash attention, causal -------------------------------
// block = 256 thr (4 waves), q-tile = 128 rows (32/wave), kv-tile = 64.
__global__ __launch_bounds__(256) void attn_kernel(
    const u16* __restrict__ Qw, const u16* __restrict__ Kw,
    const u16* __restrict__ Vt, u16* __restrict__ ctx) {
  __shared__ __align__(16) u16 Ks[64 * 64];
  __shared__ __align__(16) u16 Vs[64 * 64];   // [d][k]
  __shared__ __align__(16) u16 Ps[4][32 * 64];

  const int tid = threadIdx.x, lane = tid & 63, wid = tid >> 6;
  const int l15 = lane & 15, lg = lane >> 4;
  const int q0 = blockIdx.x * 128, bh = blockIdx.y;
  const int qw = q0 + wid * 32;
  const int b = bh >> 4, h = bh & 15;

  const u16* Qbh = Qw + (long long)bh * SS * HD;
  const u16* Kbh = Kw + (long long)bh * SS * HD;
  const u16* Vbh = Vt + (long long)bh * HD * SS;

  // Q fragments (already scaled by 1/8)
  u16x8 qf[2][2];
#pragma unroll
  for (int mi = 0; mi < 2; ++mi)
#pragma unroll
    for (int kk = 0; kk < 2; ++kk)
      qf[mi][kk] = *(const u16x8*)(Qbh + (long long)(qw + mi * 16 + l15) * HD + kk * 32 + lg * 8);

  f32x4v acc[2][4] = {};
  float m_s[2][4], l_s[2][4];
#pragma unroll
  for (int mi = 0; mi < 2; ++mi)
#pragma unroll
    for (int r = 0; r < 4; ++r) { m_s[mi][r] = -1e30f; l_s[mi][r] = 0.f; }

  const int nkb = q0 / 64 + 2;   // tiles with kbase <= q0+127
  for (int kb = 0; kb < nkb; ++kb) {
    const int kbase = kb * 64;
#pragma unroll
    for (int i = 0; i < 2; ++i) {
      int row = i * 32 + (tid >> 3);
      int col = (tid & 7) * 8;
      async16(Kbh + (long long)(kbase + row) * HD + col, (char*)Ks + i * 4096 + tid * 16);
      async16(Vbh + (long long)row * SS + kbase + col, (char*)Vs + i * 4096 + tid * 16);
    }
    __syncthreads();

    // S = Q K^T  (rows q, cols k)
    f32x4v s[2][4];
#pragma unroll
    for (int mi = 0; mi < 2; ++mi)
#pragma unroll
      for (int ni = 0; ni < 4; ++ni) s[mi][ni] = f32x4v{0.f, 0.f, 0.f, 0.f};
#pragma unroll
    for (int kk = 0; kk < 2; ++kk) {
      u16x8 bfr[4];
#pragma unroll
      for (int ni = 0; ni < 4; ++ni)
        bfr[ni] = *(const u16x8*)&Ks[(ni * 16 + l15) * 64 + kk * 32 + lg * 8];
#pragma unroll
      for (int mi = 0; mi < 2; ++mi)
#pragma unroll
        for (int ni = 0; ni < 4; ++ni)
          s[mi][ni] = mfma16(qf[mi][kk], bfr[ni], s[mi][ni]);
    }

    // causal mask
    if (kbase + 63 > qw) {
#pragma unroll
      for (int mi = 0; mi < 2; ++mi)
#pragma unroll
        for (int ni = 0; ni < 4; ++ni) {
          int kcol = kbase + ni * 16 + l15;
#pragma unroll
          for (int r = 0; r < 4; ++r) {
            int qrow = qw + mi * 16 + lg * 4 + r;
            if (kcol > qrow) s[mi][ni][r] = -1e30f;
          }
        }
    }

    // online softmax (row state lives in lanes of same col-group; uniform per 16 lanes)
#pragma unroll
    for (int mi = 0; mi < 2; ++mi)
#pragma unroll
      for (int r = 0; r < 4; ++r) {
        float rmax = fmaxf(fmaxf(s[mi][0][r], s[mi][1][r]), fmaxf(s[mi][2][r], s[mi][3][r]));
        rmax = fmaxf(rmax, __shfl_xor(rmax, 1));
        rmax = fmaxf(rmax, __shfl_xor(rmax, 2));
        rmax = fmaxf(rmax, __shfl_xor(rmax, 4));
        rmax = fmaxf(rmax, __shfl_xor(rmax, 8));
        float newm = fmaxf(m_s[mi][r], rmax);
        float scale = __builtin_exp2f((m_s[mi][r] - newm) * L2E);
        m_s[mi][r] = newm;
        float rsum = 0.f;
#pragma unroll
        for (int ni = 0; ni < 4; ++ni) {
          float p = __builtin_exp2f((s[mi][ni][r] - newm) * L2E);
          s[mi][ni][r] = p;
          rsum += p;
        }
        rsum += __shfl_xor(rsum, 1);
        rsum += __shfl_xor(rsum, 2);
        rsum += __shfl_xor(rsum, 4);
        rsum += __shfl_xor(rsum, 8);
        l_s[mi][r] = l_s[mi][r] * scale + rsum;
#pragma unroll
        for (int di = 0; di < 4; ++di) acc[mi][di][r] *= scale;
      }

    // P -> LDS (bf16), per-wave buffer; same-wave RAW, no barrier needed
    u16* Pw = &Ps[wid][0];
#pragma unroll
    for (int mi = 0; mi < 2; ++mi)
#pragma unroll
      for (int ni = 0; ni < 4; ++ni)
#pragma unroll
        for (int r = 0; r < 4; ++r)
          Pw[(mi * 16 + lg * 4 + r) * 64 + ni * 16 + l15] = f2bf(s[mi][ni][r]);

    // O += P V
#pragma unroll
    for (int ks = 0; ks < 2; ++ks) {
      u16x8 pa[2], vb[4];
#pragma unroll
      for (int mi = 0; mi < 2; ++mi)
        pa[mi] = *(const u16x8*)&Pw[(mi * 16 + l15) * 64 + ks * 32 + lg * 8];
#pragma unroll
      for (int di = 0; di < 4; ++di)
        vb[di] = *(const u16x8*)&Vs[(di * 16 + l15) * 64 + ks * 32 + lg * 8];
#pragma unroll
      for (int mi = 0; mi < 2; ++mi)
#pragma unroll
        for (int di = 0; di < 4; ++di)
          acc[mi][di] = mfma16(pa[mi], vb[di], acc[mi][di]);
    }
    __syncthreads();
  }

  // finalize: ctx[b, q, h*64+d]
#pragma unroll
  for (int mi = 0; mi < 2; ++mi)
#pragma unroll
    for (int r = 0; r < 4; ++r) {
      float inv = 1.f / l_s[mi][r];
      int qrow = qw + mi * 16 + lg * 4 + r;
#pragma unroll
      for (int di = 0; di < 4; ++di) {
        int d = di * 16 + l15;
        ctx[((long long)(b * SS + qrow)) * DD + h * HD + d] = f2bf(acc[mi][di][r] * inv);
      }
    }
}

// ---------------- launch -----------------------------------------------------
extern "C" void kernel_launch(void* const* d_in, const int* in_sizes, int n_in,
                              void* d_out, int out_size, void* d_ws, size_t ws_size,
                              hipStream_t stream) {
  const float* inp    = (const float*)d_in[0];
  const float* w_attn = (const float*)d_in[1];
  const float* b_attn = (const float*)d_in[2];
  const float* w_proj = (const float*)d_in[3];
  const float* b_proj = (const float*)d_in[4];
  float* out = (float*)d_out;
  char* ws = (char*)d_ws;

  // workspace layout (bytes)
  const long long off_A   = 0;                       // inp bf16 [8192][1024]  16MB (reused as Qw)
  const long long off_WAt = 16777216;                // w_attn^T bf16 [3072][1024]  6MB
  const long long off_WPt = 23068672;                // w_proj^T bf16 [1024][1024]  2MB
  const long long off_qkv = 25165824;                // qkv bf16 [8192][3072]  48MB (reused as ctx)
  const long long off_K   = 75497472;                // K  [64][2048][64] 16MB
  const long long off_Vt  = 92274688;                // Vt [64][64][2048] 16MB
  const long long need    = 109051904;
  if (ws_size < (size_t)need) return;

  u16* Abf = (u16*)(ws + off_A);
  u16* WAt = (u16*)(ws + off_WAt);
  u16* WPt = (u16*)(ws + off_WPt);
  u16* qkv = (u16*)(ws + off_qkv);
  u16* Qw  = Abf;        // reuse: Abf dead after QKV gemm
  u16* Kw  = (u16*)(ws + off_K);
  u16* Vt  = (u16*)(ws + off_Vt);
  u16* ctx = qkv;        // reuse: qkv dead after pack/transpose

  // 1. inp -> bf16
  convert_f32_bf16<<<2048, 256, 0, stream>>>(inp, Abf, (long long)MM * DD);
  // 2. weight transposes
  transpose_w<<<dim3(N3D / 32, DD / 32), dim3(32, 8), 0, stream>>>(w_attn, WAt, DD, N3D);
  transpose_w<<<dim3(DD / 32, DD / 32), dim3(32, 8), 0, stream>>>(w_proj, WPt, DD, DD);
  // 3. QKV gemm: [8192][3072] bf16
  gemm_kernel<<<dim3(N3D / 128, MM / 128), 256, 0, stream>>>(Abf, WAt, b_attn, qkv, N3D, DD, 1);
  // 4. pack Q (scaled), K
  pack_qk<<<MM, 256, 0, stream>>>(qkv, Qw, Kw);
  // 5. transpose V
  transpose_v<<<dim3(SS / 32, HD / 32, BB * HH), dim3(32, 8), 0, stream>>>(qkv, Vt);
  // 6. attention -> ctx bf16 [8192][1024]
  attn_kernel<<<dim3(SS / 128, BB * HH), 256, 0, stream>>>(Qw, Kw, Vt, ctx);
  // 7. output projection -> fp32 d_out
  gemm_kernel<<<dim3(DD / 128, MM / 128), 256, 0, stream>>>(ctx, WPt, b_proj, out, DD, DD, 0);
}